// Round 14
// baseline (153.735 us; speedup 1.0000x reference)
//
#include <hip/hip_runtime.h>

#define BATCH 65536
#define MT 96                 // rows per block
#define NBLK 683              // ceil(65536/96); last block has 64 valid rows

typedef unsigned short u16;
typedef __bf16 bf16x8 __attribute__((ext_vector_type(8)));
typedef float f32x4 __attribute__((ext_vector_type(4)));

// d_ws layout (u16 element offsets)
// WI/WH tiles: [K32-tile][g(0..3)][col(0..511)][e(0..7)] -> 16384 u16 = 32KB per tile
// WO: fragment layout [K32][col(32)][g][e]
#define WI_OFF 0
#define WH_OFF 16384
#define WO_OFF 540672
#define WS_USH 557056
// float region at (char*)ws + WS_USH*2
#define BI_F 0
#define BH_F 512
#define BO_F 1536
#define PART_F 1600           // [NBLK][2]
#define SCALE_F 4096          // [65536+32]
#define PREP_WH 65536
#define PREP_WI 2048
#define PREP_WO 2048
#define PREP_SC 1568
#define PREP_TOTAL (PREP_WH + PREP_WI + PREP_WO + PREP_SC)

__device__ inline u16 f2bf(float f) {
  union { float f; unsigned u; } v; v.f = f;
  unsigned u = v.u + 0x7fffu + ((v.u >> 16) & 1u);   // RNE
  return (u16)(u >> 16);
}

__global__ void prep_kernel(const float* __restrict__ w_in, const float* __restrict__ b_in,
                            const float* __restrict__ w_hid, const float* __restrict__ b_hid,
                            const float* __restrict__ w_out, const float* __restrict__ b_out,
                            const int* __restrict__ variant, int n,
                            u16* __restrict__ wsu, float* __restrict__ wsf)
{
  const int model = (n - 5) * 16 + variant[0];
  const int i = blockIdx.x * 256 + threadIdx.x;
  if (i < PREP_WH) {
    int col = i & 511, g = (i >> 9) & 3, K32 = (i >> 11) & 15, l = i >> 15;
    const float* src = w_hid + (size_t)model * 524288 + (size_t)l * 262144 + col * 512 + K32 * 32 + g * 8;
    u16* dst = wsu + WH_OFF + (size_t)i * 8;
    #pragma unroll
    for (int e = 0; e < 8; ++e) dst[e] = f2bf(src[e]);
  } else if (i < PREP_WH + PREP_WI) {
    int j = i - PREP_WH;
    int col = j & 511, g = (j >> 9) & 3;
    u16* dst = wsu + WI_OFF + (size_t)j * 8;
    #pragma unroll
    for (int e = 0; e < 8; ++e) {
      int k = g * 8 + e;
      dst[e] = (k < 16) ? f2bf(w_in[(size_t)model * 8192 + col * 16 + k]) : (u16)0;
    }
  } else if (i < PREP_WH + PREP_WI + PREP_WO) {
    int j = i - PREP_WH - PREP_WI;
    int g = j & 3, col = (j >> 2) & 31, K32 = j >> 7;
    u16* dst = wsu + WO_OFF + (size_t)j * 8;
    #pragma unroll
    for (int e = 0; e < 8; ++e) {
      int k = K32 * 32 + g * 8 + e;
      dst[e] = (col < 17) ? f2bf(w_out[(size_t)model * 8704 + col * 512 + k]) : (u16)0;
    }
  } else if (i < PREP_TOTAL) {
    int j = i - PREP_WH - PREP_WI - PREP_WO;
    if (j < 512)       wsf[BI_F + j] = b_in[(size_t)model * 512 + j];
    else if (j < 1536) wsf[BH_F + (j - 512)] = b_hid[(size_t)model * 1024 + (j - 512)];
    else               { int o = j - 1536; wsf[BO_F + o] = (o < 17) ? b_out[(size_t)model * 17 + o] : 0.f; }
  }
}

// xs layout: byte = row*1024 + ((col*2) ^ ((row&15)<<4))
__device__ __forceinline__ bf16x8 rdA(const char* xb, int row, int kbyte) {
  return *reinterpret_cast<const bf16x8*>(xb + row * 1024 + (kbyte ^ ((row & 15) << 4)));
}
__device__ __forceinline__ void st16(char* xb, int row, int col, u16 v) {
  *(u16*)(xb + row * 1024 + ((col * 2) ^ ((row & 15) << 4))) = v;
}

__device__ __forceinline__ void stage16(const u16* g, const u16* l) {
  __builtin_amdgcn_global_load_lds(
      (const __attribute__((address_space(1))) u16*)(uintptr_t)g,
      (__attribute__((address_space(3))) u16*)(unsigned)(uintptr_t)l,
      16, 0, 0);
}

template<int CN>
__global__ __launch_bounds__(512, 2) void fused_kernel(
    const float* __restrict__ T, const u16* __restrict__ wsu,
    const float* __restrict__ wsf, float* __restrict__ Xout, float* __restrict__ Xcout,
    float* __restrict__ errPart, float* __restrict__ scaleArr, int n_arg)
{
  const int n = CN ? CN : n_arg;
  __shared__ u16 xs[MT * 512];       // 96 KiB activations, XOR-swizzled
  __shared__ u16 bs[2 * 16384];      // 64 KiB: 2 x 32KB B-tiles (double buffer)
  // total LDS = 163840 B = full 160 KiB pool; xo/ered overlay bs after K-loops

  const int tid = threadIdx.x;
  const int blk = blockIdx.x;
  const int lane = tid & 63;
  const int wid = tid >> 6;          // 0..7
  const int l15 = lane & 15;
  const int q = lane >> 4;           // 0..3
  const int c0 = wid * 64;           // wave's column base (hidden layers)
  char* xb = (char*)xs;
  char* bsB = (char*)bs;

  // W-frag byte offsets within a staged tile: [g=q][col][8e] -> stride-1, conflict-free
  int bofs[4];
  #pragma unroll
  for (int ct = 0; ct < 4; ++ct)
    bofs[ct] = q * 8192 + (c0 + ct * 16 + l15) * 16;

  // DIAGNOSTIC (round 14): each tile staged TWICE (idempotent duplicate loads).
  // Doubles global->LDS delivery work; output bit-identical. vmcnt gates 4 -> 8.
  auto stageTile = [&](int tau) {
    if (tau > 32) return;
    const u16* src = (tau == 0) ? (wsu + WI_OFF)
                   : (tau <= 16) ? (wsu + WH_OFF + (size_t)(tau - 1) * 16384)
                                 : (wsu + WH_OFF + 262144 + (size_t)(tau - 17) * 16384);
    char* dst = bsB + ((tau & 1) << 15);
    const char* s = (const char*)src;
    #pragma unroll
    for (int c = 0; c < 4; ++c) {
      int d = tid * 16 + c * 8192;
      stage16((const u16*)(s + d), (const u16*)(dst + d));
      stage16((const u16*)(s + d), (const u16*)(dst + d));   // duplicate
    }
  };

  f32x4 acc[6][4];
  #pragma unroll
  for (int a = 0; a < 6; ++a)
    #pragma unroll
    for (int b = 0; b < 4; ++b) { f32x4 z = {0.f, 0.f, 0.f, 0.f}; acc[a][b] = z; }

  auto computeTile = [&](int buf, int kbA) {
    const char* bb = bsB + (buf << 15);
    bf16x8 av[6];
    #pragma unroll
    for (int mt = 0; mt < 6; ++mt) av[mt] = rdA(xb, mt * 16 + l15, kbA);
    #pragma unroll
    for (int ct = 0; ct < 4; ++ct) {
      bf16x8 b = *reinterpret_cast<const bf16x8*>(bb + bofs[ct]);
      #pragma unroll
      for (int mt = 0; mt < 6; ++mt)
        acc[mt][ct] = __builtin_amdgcn_mfma_f32_16x16x32_bf16(av[mt], b, acc[mt][ct], 0, 0, 0);
    }
  };

  auto epilogue = [&](const float* bias, int act) {
    float bv[4];
    #pragma unroll
    for (int ct = 0; ct < 4; ++ct) bv[ct] = bias[c0 + ct * 16 + l15];
    #pragma unroll
    for (int mt = 0; mt < 6; ++mt)
      #pragma unroll
      for (int ct = 0; ct < 4; ++ct) {
        #pragma unroll
        for (int j = 0; j < 4; ++j) {
          int row = mt * 16 + q * 4 + j;
          float z = acc[mt][ct][j] + bv[ct];
          float h = act ? fmaxf(z, 0.f) : z / (1.f + __expf(-z));
          st16(xb, row, c0 + ct * 16 + l15, f2bf(h));
        }
        f32x4 zz = {0.f, 0.f, 0.f, 0.f};
        acc[mt][ct] = zz;
      }
  };

  // ---- issue first two B-tiles immediately ----
  stageTile(0);
  stageTile(1);

  // ---- prologue: T load + normalize; 4 threads/row (384 active) ----
  {
    const int r = tid >> 2, j = tid & 3;
    if (r < MT) {
      const size_t gr = (size_t)blk * MT + r;
      const bool valid = gr < (size_t)BATCH;
      const float* tp = T + gr * n;
      float v[4]; float ss = 0.f;
      #pragma unroll
      for (int c = 0; c < 4; ++c) {
        int k = j * 4 + c;
        v[c] = (valid && k < n) ? tp[k] : 0.f;
        ss += v[c] * v[c];
      }
      ss += __shfl_xor(ss, 1); ss += __shfl_xor(ss, 2);
      float norm = sqrtf(ss < 1e-12f ? 1e-12f : ss);
      float rn = 1.f / norm;
      if (j == 0 && valid) scaleArr[gr] = sqrtf(norm);
      #pragma unroll
      for (int c = 0; c < 4; ++c) {
        st16(xb, r, j * 4 + c, f2bf(v[c] * rn));
        st16(xb, r, 16 + j * 4 + c, 0);
      }
    }
  }

  // ---- L0 (WI, tile 0): one K=32 step ----
  asm volatile("s_waitcnt vmcnt(8) lgkmcnt(0)" ::: "memory");
  __builtin_amdgcn_s_barrier();
  computeTile(0, q * 16);
  __builtin_amdgcn_s_barrier();
  stageTile(2);
  epilogue(wsf + BI_F, 0);
  asm volatile("s_waitcnt lgkmcnt(0)" ::: "memory");
  __builtin_amdgcn_s_barrier();

  // ---- L1 (tiles 1..16) ----
  #pragma unroll 1
  for (int i = 0; i < 16; ++i) {
    asm volatile("s_waitcnt vmcnt(8)" ::: "memory");
    __builtin_amdgcn_s_barrier();
    computeTile((1 + i) & 1, i * 64 + q * 16);
    __builtin_amdgcn_s_barrier();
    stageTile(3 + i);
  }
  epilogue(wsf + BH_F, 1);
  asm volatile("s_waitcnt lgkmcnt(0)" ::: "memory");
  __builtin_amdgcn_s_barrier();

  // ---- L2 (tiles 17..32) ----
  #pragma unroll 1
  for (int i = 0; i < 15; ++i) {
    asm volatile("s_waitcnt vmcnt(8)" ::: "memory");
    __builtin_amdgcn_s_barrier();
    computeTile((17 + i) & 1, i * 64 + q * 16);
    __builtin_amdgcn_s_barrier();
    stageTile(19 + i);
  }
  asm volatile("s_waitcnt vmcnt(0)" ::: "memory");
  __builtin_amdgcn_s_barrier();
  computeTile(0, 15 * 64 + q * 16);
  __builtin_amdgcn_s_barrier();
  epilogue(wsf + BH_F + 512, 1);
  asm volatile("s_waitcnt lgkmcnt(0)" ::: "memory");
  __builtin_amdgcn_s_barrier();
  // bs is now dead: overlay xo (96*20 floats) + ered (16 floats)
  float* xoB  = reinterpret_cast<float*>(bs);
  float* ered = xoB + MT * 20;

  // ---- output layer: waves 0..5, wave w -> rows w*16..+16, 32 padded cols ----
  if (wid < 6) {
    f32x4 oacc[2];
    { f32x4 z = {0.f, 0.f, 0.f, 0.f}; oacc[0] = z; oacc[1] = z; }
    const int bofs2 = l15 * 32 + q * 8;
    uint4 ob[2], on[2];
    #pragma unroll
    for (int ct = 0; ct < 2; ++ct)
      ob[ct] = *reinterpret_cast<const uint4*>(wsu + WO_OFF + (size_t)(ct * 16) * 32 + bofs2);
    #pragma unroll 1
    for (int K2 = 0; K2 < 16; K2 += 2) {
      #pragma unroll
      for (int ct = 0; ct < 2; ++ct)
        on[ct] = *reinterpret_cast<const uint4*>(wsu + WO_OFF + (size_t)(K2 + 1) * 1024 + (size_t)(ct * 16) * 32 + bofs2);
      {
        bf16x8 a = rdA(xb, wid * 16 + l15, K2 * 64 + q * 16);
        #pragma unroll
        for (int ct = 0; ct < 2; ++ct)
          oacc[ct] = __builtin_amdgcn_mfma_f32_16x16x32_bf16(
              a, __builtin_bit_cast(bf16x8, ob[ct]), oacc[ct], 0, 0, 0);
      }
      #pragma unroll
      for (int ct = 0; ct < 2; ++ct)
        ob[ct] = *reinterpret_cast<const uint4*>(wsu + WO_OFF + (size_t)((K2 + 2) & 15) * 1024 + (size_t)(ct * 16) * 32 + bofs2);
      {
        bf16x8 a = rdA(xb, wid * 16 + l15, (K2 + 1) * 64 + q * 16);
        #pragma unroll
        for (int ct = 0; ct < 2; ++ct)
          oacc[ct] = __builtin_amdgcn_mfma_f32_16x16x32_bf16(
              a, __builtin_bit_cast(bf16x8, on[ct]), oacc[ct], 0, 0, 0);
      }
    }
    #pragma unroll
    for (int ct = 0; ct < 2; ++ct)
      #pragma unroll
      for (int j = 0; j < 4; ++j) {
        int o = ct * 16 + l15;
        int row = wid * 16 + q * 4 + j;
        size_t gr = (size_t)blk * MT + row;
        if (o <= n && gr < (size_t)BATCH) {
          float val = (oacc[ct][j] + wsf[BO_F + o]) * scaleArr[gr];
          float cv = fminf(fmaxf(val, -2.f), 2.f);
          Xout[gr * (n + 1) + o] = val;
          Xcout[gr * (n + 1) + o] = cv;
          xoB[row * 20 + o] = val;
        }
      }
  }
  __syncthreads();

  // ---- distortion + squared-error partials: 4 threads/row (384 active) ----
  {
    const int r = tid >> 2, j = tid & 3;
    float e = 0.f, ec = 0.f;
    if (r < MT) {
      const size_t gr = (size_t)blk * MT + r;
      if (gr < (size_t)BATCH) {
        float x[17], cx[17];
        #pragma unroll
        for (int i = 0; i < 17; ++i) {
          float v = (i <= n) ? xoB[r * 20 + i] : 0.f;
          x[i] = v; cx[i] = fminf(fmaxf(v, -2.f), 2.f);
        }
        #pragma unroll
        for (int kk = 0; kk < 4; ++kk) {
          int k = j + 1 + kk * 4;
          if (k <= n) {
            float d = 0.f, dc = 0.f;
            #pragma unroll
            for (int i = 0; i < 16; ++i) {
              if (i + k <= 16) {
                if (i + k <= n) { d += x[i] * x[i + k]; dc += cx[i] * cx[i + k]; }
              }
            }
            float tvv = T[gr * n + (n - k)];
            float r1 = d - tvv, r2 = dc - tvv;
            e += r1 * r1; ec += r2 * r2;
          }
        }
      }
    }
    e += __shfl_xor(e, 1);  ec += __shfl_xor(ec, 1);
    e += __shfl_xor(e, 2);  ec += __shfl_xor(ec, 2);
    e += __shfl_xor(e, 4);  ec += __shfl_xor(ec, 4);
    e += __shfl_xor(e, 8);  ec += __shfl_xor(ec, 8);
    e += __shfl_xor(e, 16); ec += __shfl_xor(ec, 16);
    e += __shfl_xor(e, 32); ec += __shfl_xor(ec, 32);
    if (lane == 0) { ered[wid * 2] = e; ered[wid * 2 + 1] = ec; }
  }
  __syncthreads();
  if (tid == 0) {
    float e = 0.f, ec = 0.f;
    #pragma unroll
    for (int w = 0; w < 8; ++w) { e += ered[w * 2]; ec += ered[w * 2 + 1]; }
    errPart[blk * 2]     = e;
    errPart[blk * 2 + 1] = ec;
  }
}

__global__ void finalize_kernel(const float* __restrict__ part, float* __restrict__ e0,
                                float* __restrict__ e1, float inv)
{
  __shared__ float se[4][2];
  const int t = threadIdx.x;           // 256 threads
  float e = 0.f, ec = 0.f;
  for (int b = t; b < NBLK; b += 256) { e += part[2 * b]; ec += part[2 * b + 1]; }
  e += __shfl_xor(e, 1);  ec += __shfl_xor(ec, 1);
  e += __shfl_xor(e, 2);  ec += __shfl_xor(ec, 2);
  e += __shfl_xor(e, 4);  ec += __shfl_xor(ec, 4);
  e += __shfl_xor(e, 8);  ec += __shfl_xor(ec, 8);
  e += __shfl_xor(e, 16); ec += __shfl_xor(ec, 16);
  e += __shfl_xor(e, 32); ec += __shfl_xor(ec, 32);
  if ((t & 63) == 0) { se[t >> 6][0] = e; se[t >> 6][1] = ec; }
  __syncthreads();
  if (t == 0) {
    float te = 0.f, tec = 0.f;
    #pragma unroll
    for (int w = 0; w < 4; ++w) { te += se[w][0]; tec += se[w][1]; }
    e0[0] = te * inv;
    e1[0] = tec * inv;
  }
}

extern "C" void kernel_launch(void* const* d_in, const int* in_sizes, int n_in,
                              void* d_out, int out_size, void* d_ws, size_t ws_size,
                              hipStream_t stream)
{
  const float* T       = (const float*)d_in[0];
  const int*   variant = (const int*)d_in[2];
  const float* w_in    = (const float*)d_in[3];
  const float* b_in    = (const float*)d_in[4];
  const float* w_hid   = (const float*)d_in[5];
  const float* b_hid   = (const float*)d_in[6];
  const float* w_out   = (const float*)d_in[7];
  const float* b_out   = (const float*)d_in[8];
  const int n = in_sizes[0] / BATCH;

  u16* wsu = (u16*)d_ws;
  float* wsf = (float*)((char*)d_ws + (size_t)WS_USH * 2);
  float* out = (float*)d_out;
  const size_t xe = (size_t)BATCH * (n + 1);
  float* Xo  = out;
  float* eP  = out + xe;
  float* Xc  = out + xe + 1;
  float* ecP = out + 2 * xe + 1;

  const int prepBlocks = (PREP_TOTAL + 255) / 256;
  prep_kernel<<<prepBlocks, 256, 0, stream>>>(w_in, b_in, w_hid, b_hid, w_out, b_out,
                                              variant, n, wsu, wsf);
  if (n == 16)
    fused_kernel<16><<<NBLK, 512, 0, stream>>>(T, wsu, wsf, Xo, Xc, wsf + PART_F,
                                               wsf + SCALE_F, n);
  else
    fused_kernel<0><<<NBLK, 512, 0, stream>>>(T, wsu, wsf, Xo, Xc, wsf + PART_F,
                                              wsf + SCALE_F, n);
  finalize_kernel<<<1, 256, 0, stream>>>(wsf + PART_F, eP, ecP, 1.f / (float)((size_t)BATCH * n));
}

// Round 15
// 132.304 us; speedup vs baseline: 1.1620x; 1.1620x over previous
//
#include <hip/hip_runtime.h>

#define BATCH 65536
#define MT 96                 // rows per block
#define NBLK 683              // ceil(65536/96); last block has 64 valid rows

typedef unsigned short u16;
typedef __bf16 bf16x8 __attribute__((ext_vector_type(8)));
typedef float f32x4 __attribute__((ext_vector_type(4)));

// d_ws layout (u16 element offsets)
// WI/WH tiles: [K32-tile][g(0..3)][col(0..511)][e(0..7)] -> 16384 u16 = 32KB per tile
// WO: fragment layout [K32][col(32)][g][e]
#define WI_OFF 0
#define WH_OFF 16384
#define WO_OFF 540672
#define WS_USH 557056
// float region at (char*)ws + WS_USH*2
#define BI_F 0
#define BH_F 512
#define BO_F 1536
#define PART_F 1600           // [NBLK][2]
#define SCALE_F 4096          // [65536+32]
#define PREP_WH 65536
#define PREP_WI 2048
#define PREP_WO 2048
#define PREP_SC 1568
#define PREP_TOTAL (PREP_WH + PREP_WI + PREP_WO + PREP_SC)

__device__ inline u16 f2bf(float f) {
  union { float f; unsigned u; } v; v.f = f;
  unsigned u = v.u + 0x7fffu + ((v.u >> 16) & 1u);   // RNE
  return (u16)(u >> 16);
}

__global__ void prep_kernel(const float* __restrict__ w_in, const float* __restrict__ b_in,
                            const float* __restrict__ w_hid, const float* __restrict__ b_hid,
                            const float* __restrict__ w_out, const float* __restrict__ b_out,
                            const int* __restrict__ variant, int n,
                            u16* __restrict__ wsu, float* __restrict__ wsf)
{
  const int model = (n - 5) * 16 + variant[0];
  const int i = blockIdx.x * 256 + threadIdx.x;
  if (i < PREP_WH) {
    int col = i & 511, g = (i >> 9) & 3, K32 = (i >> 11) & 15, l = i >> 15;
    const float* src = w_hid + (size_t)model * 524288 + (size_t)l * 262144 + col * 512 + K32 * 32 + g * 8;
    u16* dst = wsu + WH_OFF + (size_t)i * 8;
    #pragma unroll
    for (int e = 0; e < 8; ++e) dst[e] = f2bf(src[e]);
  } else if (i < PREP_WH + PREP_WI) {
    int j = i - PREP_WH;
    int col = j & 511, g = (j >> 9) & 3;
    u16* dst = wsu + WI_OFF + (size_t)j * 8;
    #pragma unroll
    for (int e = 0; e < 8; ++e) {
      int k = g * 8 + e;
      dst[e] = (k < 16) ? f2bf(w_in[(size_t)model * 8192 + col * 16 + k]) : (u16)0;
    }
  } else if (i < PREP_WH + PREP_WI + PREP_WO) {
    int j = i - PREP_WH - PREP_WI;
    int g = j & 3, col = (j >> 2) & 31, K32 = j >> 7;
    u16* dst = wsu + WO_OFF + (size_t)j * 8;
    #pragma unroll
    for (int e = 0; e < 8; ++e) {
      int k = K32 * 32 + g * 8 + e;
      dst[e] = (col < 17) ? f2bf(w_out[(size_t)model * 8704 + col * 512 + k]) : (u16)0;
    }
  } else if (i < PREP_TOTAL) {
    int j = i - PREP_WH - PREP_WI - PREP_WO;
    if (j < 512)       wsf[BI_F + j] = b_in[(size_t)model * 512 + j];
    else if (j < 1536) wsf[BH_F + (j - 512)] = b_hid[(size_t)model * 1024 + (j - 512)];
    else               { int o = j - 1536; wsf[BO_F + o] = (o < 17) ? b_out[(size_t)model * 17 + o] : 0.f; }
  }
}

// xs layout: byte = row*1024 + ((col*2) ^ ((row&15)<<4))
__device__ __forceinline__ bf16x8 rdA(const char* xb, int row, int kbyte) {
  return *reinterpret_cast<const bf16x8*>(xb + row * 1024 + (kbyte ^ ((row & 15) << 4)));
}
__device__ __forceinline__ void st16(char* xb, int row, int col, u16 v) {
  *(u16*)(xb + row * 1024 + ((col * 2) ^ ((row & 15) << 4))) = v;
}

__device__ __forceinline__ void stage16(const u16* g, const u16* l) {
  __builtin_amdgcn_global_load_lds(
      (const __attribute__((address_space(1))) u16*)(uintptr_t)g,
      (__attribute__((address_space(3))) u16*)(unsigned)(uintptr_t)l,
      16, 0, 0);
}

template<int CN>
__global__ __launch_bounds__(512, 2) void fused_kernel(
    const float* __restrict__ T, const u16* __restrict__ wsu,
    const float* __restrict__ wsf, float* __restrict__ Xout, float* __restrict__ Xcout,
    float* __restrict__ errPart, float* __restrict__ scaleArr, int n_arg)
{
  const int n = CN ? CN : n_arg;
  __shared__ u16 xs[MT * 512];       // 96 KiB activations, XOR-swizzled
  __shared__ u16 bs[2 * 16384];      // 64 KiB: 2 x 32KB B-tiles (double buffer)
  // total LDS = 163840 B; xo/ered overlay bs after K-loops

  const int tid = threadIdx.x;
  const int blk = blockIdx.x;
  const int lane = tid & 63;
  const int wid = tid >> 6;          // 0..7
  const int l15 = lane & 15;
  const int q = lane >> 4;           // 0..3
  const int c0 = wid * 64;           // wave's column base (hidden layers)
  char* xb = (char*)xs;
  char* bsB = (char*)bs;

  // W-frag byte offsets within a staged tile: [g=q][col][8e] -> stride-1, conflict-free
  int bofs[4];
  #pragma unroll
  for (int ct = 0; ct < 4; ++ct)
    bofs[ct] = q * 8192 + (c0 + ct * 16 + l15) * 16;

  auto stageTile = [&](int tau) {
    if (tau > 32) return;
    const u16* src = (tau == 0) ? (wsu + WI_OFF)
                   : (tau <= 16) ? (wsu + WH_OFF + (size_t)(tau - 1) * 16384)
                                 : (wsu + WH_OFF + 262144 + (size_t)(tau - 17) * 16384);
    char* dst = bsB + ((tau & 1) << 15);
    const char* s = (const char*)src;
    #pragma unroll
    for (int c = 0; c < 4; ++c) {
      int d = tid * 16 + c * 8192;
      stage16((const u16*)(s + d), (const u16*)(dst + d));
    }
  };

  f32x4 acc[6][4];
  #pragma unroll
  for (int a = 0; a < 6; ++a)
    #pragma unroll
    for (int b = 0; b < 4; ++b) { f32x4 z = {0.f, 0.f, 0.f, 0.f}; acc[a][b] = z; }

  // SWAPPED operands: A = W-frag (M = out col), B = X-frag (N = batch row).
  // acc[mt][ct][j] = out[batch = mt*16 + l15][col = c0 + ct*16 + q*4 + j]
  auto computeTile = [&](int buf, int kbA) {
    const char* bb = bsB + (buf << 15);
    bf16x8 av[6], wv[4];
    #pragma unroll
    for (int mt = 0; mt < 6; ++mt) av[mt] = rdA(xb, mt * 16 + l15, kbA);
    #pragma unroll
    for (int ct = 0; ct < 4; ++ct) wv[ct] = *reinterpret_cast<const bf16x8*>(bb + bofs[ct]);
    #pragma unroll
    for (int ct = 0; ct < 4; ++ct)
      #pragma unroll
      for (int mt = 0; mt < 6; ++mt)
        acc[mt][ct] = __builtin_amdgcn_mfma_f32_16x16x32_bf16(wv[ct], av[mt], acc[mt][ct], 0, 0, 0);
  };

  // packed epilogue: lane holds 4 consecutive cols of one row -> uint2 LDS write
  auto epilogue = [&](const float* bias, int act) {
    #pragma unroll
    for (int ct = 0; ct < 4; ++ct) {
      float4 bv = *reinterpret_cast<const float4*>(bias + c0 + ct * 16 + q * 4);
      const int colb = (c0 + ct * 16 + q * 4) * 2;
      #pragma unroll
      for (int mt = 0; mt < 6; ++mt) {
        int row = mt * 16 + l15;
        float z0 = acc[mt][ct][0] + bv.x;
        float z1 = acc[mt][ct][1] + bv.y;
        float z2 = acc[mt][ct][2] + bv.z;
        float z3 = acc[mt][ct][3] + bv.w;
        float h0, h1, h2, h3;
        if (act) {
          h0 = fmaxf(z0, 0.f); h1 = fmaxf(z1, 0.f); h2 = fmaxf(z2, 0.f); h3 = fmaxf(z3, 0.f);
        } else {
          h0 = z0 / (1.f + __expf(-z0)); h1 = z1 / (1.f + __expf(-z1));
          h2 = z2 / (1.f + __expf(-z2)); h3 = z3 / (1.f + __expf(-z3));
        }
        uint2 wv2;
        wv2.x = (unsigned)f2bf(h0) | ((unsigned)f2bf(h1) << 16);
        wv2.y = (unsigned)f2bf(h2) | ((unsigned)f2bf(h3) << 16);
        *reinterpret_cast<uint2*>(xb + row * 1024 + (colb ^ ((row & 15) << 4))) = wv2;
        f32x4 zz = {0.f, 0.f, 0.f, 0.f};
        acc[mt][ct] = zz;
      }
    }
  };

  // ---- issue first two B-tiles immediately ----
  stageTile(0);
  stageTile(1);

  // ---- prologue: T load + normalize; 4 threads/row (384 active) ----
  {
    const int r = tid >> 2, j = tid & 3;
    if (r < MT) {
      const size_t gr = (size_t)blk * MT + r;
      const bool valid = gr < (size_t)BATCH;
      const float* tp = T + gr * n;
      float v[4]; float ss = 0.f;
      #pragma unroll
      for (int c = 0; c < 4; ++c) {
        int k = j * 4 + c;
        v[c] = (valid && k < n) ? tp[k] : 0.f;
        ss += v[c] * v[c];
      }
      ss += __shfl_xor(ss, 1); ss += __shfl_xor(ss, 2);
      float norm = sqrtf(ss < 1e-12f ? 1e-12f : ss);
      float rn = 1.f / norm;
      if (j == 0 && valid) scaleArr[gr] = sqrtf(norm);
      #pragma unroll
      for (int c = 0; c < 4; ++c) {
        st16(xb, r, j * 4 + c, f2bf(v[c] * rn));
        st16(xb, r, 16 + j * 4 + c, 0);
      }
    }
  }

  // ---- L0 (WI, tile 0): one K=32 step ----
  asm volatile("s_waitcnt vmcnt(4) lgkmcnt(0)" ::: "memory");
  __builtin_amdgcn_s_barrier();
  computeTile(0, q * 16);
  __builtin_amdgcn_s_barrier();
  stageTile(2);
  epilogue(wsf + BI_F, 0);
  asm volatile("s_waitcnt lgkmcnt(0)" ::: "memory");
  __builtin_amdgcn_s_barrier();

  // ---- L1 (tiles 1..16) ----
  #pragma unroll 1
  for (int i = 0; i < 16; ++i) {
    asm volatile("s_waitcnt vmcnt(4)" ::: "memory");
    __builtin_amdgcn_s_barrier();
    computeTile((1 + i) & 1, i * 64 + q * 16);
    __builtin_amdgcn_s_barrier();
    stageTile(3 + i);
  }
  epilogue(wsf + BH_F, 1);
  asm volatile("s_waitcnt lgkmcnt(0)" ::: "memory");
  __builtin_amdgcn_s_barrier();

  // ---- L2 (tiles 17..32) ----
  #pragma unroll 1
  for (int i = 0; i < 15; ++i) {
    asm volatile("s_waitcnt vmcnt(4)" ::: "memory");
    __builtin_amdgcn_s_barrier();
    computeTile((17 + i) & 1, i * 64 + q * 16);
    __builtin_amdgcn_s_barrier();
    stageTile(19 + i);
  }
  asm volatile("s_waitcnt vmcnt(0)" ::: "memory");
  __builtin_amdgcn_s_barrier();
  computeTile(0, 15 * 64 + q * 16);
  __builtin_amdgcn_s_barrier();
  epilogue(wsf + BH_F + 512, 1);
  asm volatile("s_waitcnt lgkmcnt(0)" ::: "memory");
  __builtin_amdgcn_s_barrier();
  // bs is now dead: overlay xo (96*20 floats) + ered (16 floats)
  float* xoB  = reinterpret_cast<float*>(bs);
  float* ered = xoB + MT * 20;

  // ---- output layer (swapped): waves 0..5, wave w -> rows w*16..+16, 32 padded cols ----
  if (wid < 6) {
    f32x4 oacc[2];
    { f32x4 z = {0.f, 0.f, 0.f, 0.f}; oacc[0] = z; oacc[1] = z; }
    const int bofs2 = l15 * 32 + q * 8;
    uint4 ob[2], on[2];
    #pragma unroll
    for (int ct = 0; ct < 2; ++ct)
      ob[ct] = *reinterpret_cast<const uint4*>(wsu + WO_OFF + (size_t)(ct * 16) * 32 + bofs2);
    #pragma unroll 1
    for (int K2 = 0; K2 < 16; K2 += 2) {
      #pragma unroll
      for (int ct = 0; ct < 2; ++ct)
        on[ct] = *reinterpret_cast<const uint4*>(wsu + WO_OFF + (size_t)(K2 + 1) * 1024 + (size_t)(ct * 16) * 32 + bofs2);
      {
        bf16x8 a = rdA(xb, wid * 16 + l15, K2 * 64 + q * 16);
        #pragma unroll
        for (int ct = 0; ct < 2; ++ct)
          oacc[ct] = __builtin_amdgcn_mfma_f32_16x16x32_bf16(
              __builtin_bit_cast(bf16x8, ob[ct]), a, oacc[ct], 0, 0, 0);
      }
      #pragma unroll
      for (int ct = 0; ct < 2; ++ct)
        ob[ct] = *reinterpret_cast<const uint4*>(wsu + WO_OFF + (size_t)((K2 + 2) & 15) * 1024 + (size_t)(ct * 16) * 32 + bofs2);
      {
        bf16x8 a = rdA(xb, wid * 16 + l15, (K2 + 1) * 64 + q * 16);
        #pragma unroll
        for (int ct = 0; ct < 2; ++ct)
          oacc[ct] = __builtin_amdgcn_mfma_f32_16x16x32_bf16(
              __builtin_bit_cast(bf16x8, on[ct]), a, oacc[ct], 0, 0, 0);
      }
    }
    // swapped C-map: lane -> batch row = wid*16 + l15 (fixed), o = ct*16 + q*4 + j
    const int row = wid * 16 + l15;
    const size_t gr = (size_t)blk * MT + row;
    if (gr < (size_t)BATCH) {
      const float sc = scaleArr[gr];
      #pragma unroll
      for (int ct = 0; ct < 2; ++ct) {
        float4 bo = *reinterpret_cast<const float4*>(wsf + BO_F + ct * 16 + q * 4);
        float vv[4] = {(oacc[ct][0] + bo.x) * sc, (oacc[ct][1] + bo.y) * sc,
                       (oacc[ct][2] + bo.z) * sc, (oacc[ct][3] + bo.w) * sc};
        #pragma unroll
        for (int j = 0; j < 4; ++j) {
          int o = ct * 16 + q * 4 + j;
          if (o <= n) {
            float cv = fminf(fmaxf(vv[j], -2.f), 2.f);
            Xout[gr * (n + 1) + o] = vv[j];
            Xcout[gr * (n + 1) + o] = cv;
            xoB[row * 20 + o] = vv[j];
          }
        }
      }
    }
  }
  __syncthreads();

  // ---- distortion + squared-error partials: 4 threads/row (384 active) ----
  {
    const int r = tid >> 2, j = tid & 3;
    float e = 0.f, ec = 0.f;
    if (r < MT) {
      const size_t gr = (size_t)blk * MT + r;
      if (gr < (size_t)BATCH) {
        float x[17], cx[17];
        #pragma unroll
        for (int i = 0; i < 17; ++i) {
          float v = (i <= n) ? xoB[r * 20 + i] : 0.f;
          x[i] = v; cx[i] = fminf(fmaxf(v, -2.f), 2.f);
        }
        #pragma unroll
        for (int kk = 0; kk < 4; ++kk) {
          int k = j + 1 + kk * 4;
          if (k <= n) {
            float d = 0.f, dc = 0.f;
            #pragma unroll
            for (int i = 0; i < 16; ++i) {
              if (i + k <= 16) {
                if (i + k <= n) { d += x[i] * x[i + k]; dc += cx[i] * cx[i + k]; }
              }
            }
            float tvv = T[gr * n + (n - k)];
            float r1 = d - tvv, r2 = dc - tvv;
            e += r1 * r1; ec += r2 * r2;
          }
        }
      }
    }
    e += __shfl_xor(e, 1);  ec += __shfl_xor(ec, 1);
    e += __shfl_xor(e, 2);  ec += __shfl_xor(ec, 2);
    e += __shfl_xor(e, 4);  ec += __shfl_xor(ec, 4);
    e += __shfl_xor(e, 8);  ec += __shfl_xor(ec, 8);
    e += __shfl_xor(e, 16); ec += __shfl_xor(ec, 16);
    e += __shfl_xor(e, 32); ec += __shfl_xor(ec, 32);
    if (lane == 0) { ered[wid * 2] = e; ered[wid * 2 + 1] = ec; }
  }
  __syncthreads();
  if (tid == 0) {
    float e = 0.f, ec = 0.f;
    #pragma unroll
    for (int w = 0; w < 8; ++w) { e += ered[w * 2]; ec += ered[w * 2 + 1]; }
    errPart[blk * 2]     = e;
    errPart[blk * 2 + 1] = ec;
  }
}

__global__ void finalize_kernel(const float* __restrict__ part, float* __restrict__ e0,
                                float* __restrict__ e1, float inv)
{
  __shared__ float se[4][2];
  const int t = threadIdx.x;           // 256 threads
  float e = 0.f, ec = 0.f;
  for (int b = t; b < NBLK; b += 256) { e += part[2 * b]; ec += part[2 * b + 1]; }
  e += __shfl_xor(e, 1);  ec += __shfl_xor(ec, 1);
  e += __shfl_xor(e, 2);  ec += __shfl_xor(ec, 2);
  e += __shfl_xor(e, 4);  ec += __shfl_xor(ec, 4);
  e += __shfl_xor(e, 8);  ec += __shfl_xor(ec, 8);
  e += __shfl_xor(e, 16); ec += __shfl_xor(ec, 16);
  e += __shfl_xor(e, 32); ec += __shfl_xor(ec, 32);
  if ((t & 63) == 0) { se[t >> 6][0] = e; se[t >> 6][1] = ec; }
  __syncthreads();
  if (t == 0) {
    float te = 0.f, tec = 0.f;
    #pragma unroll
    for (int w = 0; w < 4; ++w) { te += se[w][0]; tec += se[w][1]; }
    e0[0] = te * inv;
    e1[0] = tec * inv;
  }
}

extern "C" void kernel_launch(void* const* d_in, const int* in_sizes, int n_in,
                              void* d_out, int out_size, void* d_ws, size_t ws_size,
                              hipStream_t stream)
{
  const float* T       = (const float*)d_in[0];
  const int*   variant = (const int*)d_in[2];
  const float* w_in    = (const float*)d_in[3];
  const float* b_in    = (const float*)d_in[4];
  const float* w_hid   = (const float*)d_in[5];
  const float* b_hid   = (const float*)d_in[6];
  const float* w_out   = (const float*)d_in[7];
  const float* b_out   = (const float*)d_in[8];
  const int n = in_sizes[0] / BATCH;

  u16* wsu = (u16*)d_ws;
  float* wsf = (float*)((char*)d_ws + (size_t)WS_USH * 2);
  float* out = (float*)d_out;
  const size_t xe = (size_t)BATCH * (n + 1);
  float* Xo  = out;
  float* eP  = out + xe;
  float* Xc  = out + xe + 1;
  float* ecP = out + 2 * xe + 1;

  const int prepBlocks = (PREP_TOTAL + 255) / 256;
  prep_kernel<<<prepBlocks, 256, 0, stream>>>(w_in, b_in, w_hid, b_hid, w_out, b_out,
                                              variant, n, wsu, wsf);
  if (n == 16)
    fused_kernel<16><<<NBLK, 512, 0, stream>>>(T, wsu, wsf, Xo, Xc, wsf + PART_F,
                                               wsf + SCALE_F, n);
  else
    fused_kernel<0><<<NBLK, 512, 0, stream>>>(T, wsu, wsf, Xo, Xc, wsf + PART_F,
                                              wsf + SCALE_F, n);
  finalize_kernel<<<1, 256, 0, stream>>>(wsf + PART_F, eP, ecP, 1.f / (float)((size_t)BATCH * n));
}